// Round 5
// baseline (241.472 us; speedup 1.0000x reference)
//
#include <hip/hip_runtime.h>

#define NB   64
#define NT   256
#define NI   512
#define NO   512
#define NOBS 128
#define ETA  0.01f

typedef __attribute__((ext_vector_type(8))) short bf16x8;
typedef __attribute__((ext_vector_type(4))) float f32x4;

#define X4_COUNT  (NB*NT*NI/4)      // 2,097,152 float4s of X
#define WG4_COUNT (NB*NOBS*NI/4)    // 1,048,576 float4s of gathered W
#define K0_TOTAL  (X4_COUNT + WG4_COUNT)

__device__ __forceinline__ unsigned short f2bf(float f) {
    unsigned int u = __float_as_uint(f);
    return (unsigned short)((u + 0x7fffu + ((u >> 16) & 1u)) >> 16); // RNE
}

// ---------------- K0: X -> bf16 ; gather obs rows of W -> bf16 ----------------
__global__ __launch_bounds__(256)
void k0_convert(const float* __restrict__ X, const float* __restrict__ Wi,
                const int* __restrict__ obs,
                unsigned short* __restrict__ Xb, unsigned short* __restrict__ Wg)
{
    int idx = blockIdx.x * 256 + threadIdx.x;
    const int stride = gridDim.x * 256;
    for (; idx < K0_TOTAL; idx += stride) {
        float4 v; ushort4* dst;
        if (idx < X4_COUNT) {
            v = ((const float4*)X)[idx];
            dst = (ushort4*)Xb + idx;
        } else {
            int g = idx - X4_COUNT;
            int row = g >> 7, pos = g & 127;   // 128 float4 per 512-row
            int b = row >> 7, j = row & 127;
            v = ((const float4*)(Wi + ((size_t)b * NO + obs[j]) * NI))[pos];
            dst = (ushort4*)Wg + ((size_t)row * 128 + pos);
        }
        *dst = make_ushort4(f2bf(v.x), f2bf(v.y), f2bf(v.z), f2bf(v.w));
    }
}

// ---------------- K1: G = Xb Xb^T (fp32) ; P0 = Xb Wg^T (fp32) ----------------
// mfma_f32_16x16x32_bf16: A[m=lane&15][k=quad*8+j], B[n=lane&15][k=quad*8+j],
// D[m=quad*4+r][n=lane&15]  (m89/m91/m120-verified layouts)
__global__ __launch_bounds__(256)
void k1_gemm(const unsigned short* __restrict__ Xb,
             const unsigned short* __restrict__ Wg,
             float* __restrict__ G, float* __restrict__ P0)
{
    const int tid  = threadIdx.x;
    const int lane = tid & 63;
    const int wv   = tid >> 6;
    const int l16  = lane & 15;
    const int koff = (lane >> 4) * 8;
    const int quad = lane >> 4;

    if (blockIdx.x < NB * 8) {                 // ---- G part: 8 blocks/batch
        const int b  = blockIdx.x >> 3;
        const int m0 = (((blockIdx.x & 7) * 2) + (wv >> 1)) * 16;
        const int nbase = (wv & 1) * 8;
        const unsigned short* xbB = Xb + (size_t)b * NT * NI;
        bf16x8 a[16];
#pragma unroll
        for (int kk = 0; kk < 16; ++kk)
            a[kk] = *(const bf16x8*)(xbB + (size_t)(m0 + l16) * NI + kk * 32 + koff);
        float* Gb = G + (size_t)b * NT * NT;
#pragma unroll
        for (int nt = 0; nt < 8; ++nt) {
            const int n0 = (nbase + nt) * 16;
            f32x4 acc = {0.f, 0.f, 0.f, 0.f};
            const unsigned short* brow = xbB + (size_t)(n0 + l16) * NI + koff;
#pragma unroll
            for (int kk = 0; kk < 16; ++kk)
                acc = __builtin_amdgcn_mfma_f32_16x16x32_bf16(
                    a[kk], *(const bf16x8*)(brow + kk * 32), acc, 0, 0, 0);
#pragma unroll
            for (int r = 0; r < 4; ++r)
                Gb[(size_t)(m0 + quad * 4 + r) * NT + n0 + l16] = acc[r];
        }
    } else {                                   // ---- P0 part: 4 blocks/batch
        const int pblk = blockIdx.x - NB * 8;
        const int b  = pblk >> 2;
        const int m0 = ((pblk & 3) * 4 + wv) * 16;
        const unsigned short* xbB = Xb + (size_t)b * NT * NI;
        const unsigned short* wgB = Wg + (size_t)b * NOBS * NI;
        bf16x8 a[16];
#pragma unroll
        for (int kk = 0; kk < 16; ++kk)
            a[kk] = *(const bf16x8*)(xbB + (size_t)(m0 + l16) * NI + kk * 32 + koff);
        float* Pb = P0 + (size_t)b * NT * NOBS;
#pragma unroll
        for (int nt = 0; nt < 8; ++nt) {
            const int n0 = nt * 16;
            f32x4 acc = {0.f, 0.f, 0.f, 0.f};
            const unsigned short* brow = wgB + (size_t)(n0 + l16) * NI + koff;
#pragma unroll
            for (int kk = 0; kk < 16; ++kk)
                acc = __builtin_amdgcn_mfma_f32_16x16x32_bf16(
                    a[kk], *(const bf16x8*)(brow + kk * 32), acc, 0, 0, 0);
#pragma unroll
            for (int r = 0; r < 4; ++r)
                Pb[(size_t)(m0 + quad * 4 + r) * NOBS + n0 + l16] = acc[r];
        }
    }
}

// ---------------- K2: blocked forward-substitution scan ----------------
// block = (batch b, 16 j's). thread (j=tid&15, s=tid>>4) owns pre[t] for
// t in [16s,16s+16). chunk c: threads s==c run the 16 serial sigmoid steps
// (G diag blocks pre-staged in LDS); threads s>c apply the rank-16 update.
__global__ __launch_bounds__(256)
void k2_scan(const float* __restrict__ G, const float* __restrict__ P0,
             float* __restrict__ out)
{
    __shared__ float gdiag[16 * 16 * 16];   // [c][u][v] 16 KB
    __shared__ float ylds[16 * 16];         // [u][j]

    const int tid = threadIdx.x;
    const int j = tid & 15;
    const int s = tid >> 4;
    const int b  = blockIdx.x >> 3;
    const int jb = blockIdx.x & 7;

    const float* Gb = G  + (size_t)b * NT * NT;
    const float* Pb = P0 + (size_t)b * NT * NOBS;

    // stage all 16 diagonal 16x16 blocks of G into LDS (1024 float4 loads)
#pragma unroll
    for (int it = 0; it < 4; ++it) {
        int fi = it * 256 + tid;
        int c = fi >> 6, u = (fi >> 2) & 15, v4 = fi & 3;
        ((f32x4*)gdiag)[fi] =
            *(const f32x4*)&Gb[(size_t)(c * 16 + u) * NT + c * 16 + v4 * 4];
    }
    __syncthreads();

    float pre[16];
#pragma unroll
    for (int v = 0; v < 16; ++v)
        pre[v] = Pb[(size_t)(s * 16 + v) * NOBS + jb * 16 + j];

    float* ob = out + (size_t)b * NT * NOBS + jb * 16 + j;

    for (int c = 0; c < 16; ++c) {
        if (s == c) {
            // ---- serial phase: 16 sigmoid steps, diag G from LDS (ping-pong)
            const float* gd = gdiag + c * 256;
            f32x4 r0[4], r1[4];
#pragma unroll
            for (int q = 0; q < 4; ++q) r0[q] = ((const f32x4*)gd)[q];
#pragma unroll
            for (int q = 0; q < 4; ++q) r1[q] = ((const f32x4*)(gd + 16))[q];
#pragma unroll
            for (int u = 0; u < 16; ++u) {
                const float y = 1.f / (1.f + __expf(-pre[u]));
                ylds[u * 16 + j] = y;
                ob[(size_t)(c * 16 + u) * NOBS] = y;
                const float e = ETA * y;
                const float* g = (const float*)((u & 1) ? r1 : r0);
#pragma unroll
                for (int v = 0; v < 16; ++v)
                    if (v > u) pre[v] = fmaf(e, g[v], pre[v]);
                if (u + 2 < 16) {
                    f32x4* tgt = (u & 1) ? r1 : r0;
#pragma unroll
                    for (int q = 0; q < 4; ++q)
                        tgt[q] = ((const f32x4*)(gd + (u + 2) * 16))[q];
                }
            }
        }
        __syncthreads();
        if (s > c) {
            // ---- parallel rank-16 update of my 16 future pre's
            const int col0 = s * 16;
#pragma unroll
            for (int u = 0; u < 16; ++u) {
                const float e = ETA * ylds[u * 16 + j];
                const float* grow = Gb + (size_t)(c * 16 + u) * NT + col0;
                f32x4 gv[4];
#pragma unroll
                for (int q = 0; q < 4; ++q) gv[q] = ((const f32x4*)grow)[q];
                const float* g = (const float*)gv;
#pragma unroll
                for (int v = 0; v < 16; ++v)
                    pre[v] = fmaf(e, g[v], pre[v]);
            }
        }
        __syncthreads();
    }
}

extern "C" void kernel_launch(void* const* d_in, const int* in_sizes, int n_in,
                              void* d_out, int out_size, void* d_ws, size_t ws_size,
                              hipStream_t stream)
{
    const float* X   = (const float*)d_in[0];
    const float* Wi  = (const float*)d_in[1];
    const int*   obs = (const int*)d_in[2];
    float*       out = (float*)d_out;

    unsigned short* Xb = (unsigned short*)d_ws;                          // 16 MB
    unsigned short* Wg = (unsigned short*)((char*)d_ws + (16u << 20));   //  8 MB
    float*          G  = (float*)((char*)d_ws + (24u << 20));            // 16 MB
    float*          P0 = (float*)((char*)d_ws + (40u << 20));            //  8 MB

    hipLaunchKernelGGL(k0_convert, dim3(3072), dim3(256), 0, stream,
                       X, Wi, obs, Xb, Wg);
    hipLaunchKernelGGL(k1_gemm, dim3(NB * 8 + NB * 4), dim3(256), 0, stream,
                       Xb, Wg, G, P0);
    hipLaunchKernelGGL(k2_scan, dim3(NB * 8), dim3(256), 0, stream,
                       G, P0, out);
}

// Round 6
// 193.449 us; speedup vs baseline: 1.2482x; 1.2482x over previous
//
#include <hip/hip_runtime.h>

#define NB   64
#define NT   256
#define NI   512
#define NO   512
#define NOBS 128
#define ETA  0.01f

typedef __attribute__((ext_vector_type(8))) short bf16x8;
typedef __attribute__((ext_vector_type(4))) float f32x4;

#define X4_COUNT  (NB*NT*NI/4)      // 2,097,152 float4s of X
#define WG4_COUNT (NB*NOBS*NI/4)    // 1,048,576 float4s of gathered W
#define K0_TOTAL  (X4_COUNT + WG4_COUNT)

__device__ __forceinline__ unsigned short f2bf(float f) {
    unsigned int u = __float_as_uint(f);
    return (unsigned short)((u + 0x7fffu + ((u >> 16) & 1u)) >> 16); // RNE
}

// ---------------- K0: X -> bf16 ; gather obs rows of W -> bf16 ----------------
__global__ __launch_bounds__(256)
void k0_convert(const float* __restrict__ X, const float* __restrict__ Wi,
                const int* __restrict__ obs,
                unsigned short* __restrict__ Xb, unsigned short* __restrict__ Wg)
{
    int idx = blockIdx.x * 256 + threadIdx.x;
    const int stride = gridDim.x * 256;
    for (; idx < K0_TOTAL; idx += stride) {
        float4 v; ushort4* dst;
        if (idx < X4_COUNT) {
            v = ((const float4*)X)[idx];
            dst = (ushort4*)Xb + idx;
        } else {
            int g = idx - X4_COUNT;
            int row = g >> 7, pos = g & 127;   // 128 float4 per 512-row
            int b = row >> 7, j = row & 127;
            v = ((const float4*)(Wi + ((size_t)b * NO + obs[j]) * NI))[pos];
            dst = (ushort4*)Wg + ((size_t)row * 128 + pos);
        }
        *dst = make_ushort4(f2bf(v.x), f2bf(v.y), f2bf(v.z), f2bf(v.w));
    }
}

// ---------------- K1: LDS-tiled bf16 MFMA GEMM ----------------
// 5 blocks per batch: sub 0..2 -> G upper blocks {(0,0),(0,1),(1,1)}
//                     sub 3..4 -> P0 row-blocks {0,1}
// tile 128x128, BK=64. XOR-swizzled LDS (16B chunk c stored at slot c^(m&7))
// -> ds_write/ds_read 2-way bank aliasing only (free).
// mfma_f32_16x16x32_bf16 layouts (verified in R5): A[m=l16][k=quad*8+j],
// B[n=l16][k=quad*8+j], D[m=quad*4+r][n=l16].
__global__ __launch_bounds__(256)
void k1_gemm(const unsigned short* __restrict__ Xb,
             const unsigned short* __restrict__ Wg,
             float* __restrict__ G, float* __restrict__ P0)
{
    __shared__ unsigned short As[128 * 64];   // 16 KB
    __shared__ unsigned short Bs[128 * 64];   // 16 KB

    const int tid  = threadIdx.x;
    const int lane = tid & 63;
    const int wv   = tid >> 6;
    const int l16  = lane & 15;
    const int quad = lane >> 4;

    const int b   = blockIdx.x / 5;
    const int sub = blockIdx.x - b * 5;

    const unsigned short* xbB = Xb + (size_t)b * NT * NI;
    const unsigned short *aRows, *bRows;
    float* outp;
    int ldo;
    if (sub < 3) {
        const int bm = (sub == 2) ? 1 : 0;
        const int bn = (sub == 0) ? 0 : 1;
        aRows = xbB + (size_t)bm * 128 * NI;
        bRows = xbB + (size_t)bn * 128 * NI;
        outp  = G + (size_t)b * NT * NT + (size_t)bm * 128 * NT + bn * 128;
        ldo   = NT;
    } else {
        const int pb = sub - 3;
        aRows = xbB + (size_t)pb * 128 * NI;
        bRows = Wg + (size_t)b * NOBS * NI;
        outp  = P0 + (size_t)b * NT * NOBS + (size_t)pb * 128 * NOBS;
        ldo   = NOBS;
    }

    const int wm = (wv >> 1) * 64;
    const int wn = (wv & 1) * 64;

    f32x4 acc[4][4] = {};

    for (int kb = 0; kb < NI / 64; ++kb) {
        __syncthreads();
        // ---- stage both 128x64 tiles, coalesced, XOR-swizzled ----
#pragma unroll
        for (int it = 0; it < 4; ++it) {
            const int s = it * 256 + tid;      // chunk-slot id 0..1023
            const int m = s >> 3, c = s & 7;
            const int slot = m * 64 + ((c ^ (m & 7)) * 8);
            const size_t goff = (size_t)m * NI + kb * 64 + c * 8;
            *(bf16x8*)&As[slot] = *(const bf16x8*)(aRows + goff);
            *(bf16x8*)&Bs[slot] = *(const bf16x8*)(bRows + goff);
        }
        __syncthreads();
        // ---- 2 K-steps of 16 MFMA each ----
#pragma unroll
        for (int ks = 0; ks < 2; ++ks) {
            const int q = ks * 4 + quad;
            bf16x8 af[4], bfr[4];
#pragma unroll
            for (int mt = 0; mt < 4; ++mt) {
                const int m = wm + mt * 16 + l16;
                af[mt] = *(const bf16x8*)&As[m * 64 + ((q ^ (m & 7)) * 8)];
            }
#pragma unroll
            for (int nt = 0; nt < 4; ++nt) {
                const int n = wn + nt * 16 + l16;
                bfr[nt] = *(const bf16x8*)&Bs[n * 64 + ((q ^ (n & 7)) * 8)];
            }
#pragma unroll
            for (int mt = 0; mt < 4; ++mt)
#pragma unroll
                for (int nt = 0; nt < 4; ++nt)
                    acc[mt][nt] = __builtin_amdgcn_mfma_f32_16x16x32_bf16(
                        af[mt], bfr[nt], acc[mt][nt], 0, 0, 0);
        }
    }

#pragma unroll
    for (int mt = 0; mt < 4; ++mt)
#pragma unroll
        for (int nt = 0; nt < 4; ++nt)
#pragma unroll
            for (int r = 0; r < 4; ++r)
                outp[(size_t)(wm + mt * 16 + quad * 4 + r) * ldo
                     + wn + nt * 16 + l16] = acc[mt][nt][r];
}

// ---------------- K2: blocked forward-substitution scan ----------------
__global__ __launch_bounds__(256)
void k2_scan(const float* __restrict__ G, const float* __restrict__ P0,
             float* __restrict__ out)
{
    __shared__ float gdiag[16 * 16 * 16];   // [c][u][v] 16 KB
    __shared__ float ylds[16 * 16];         // [u][j]

    const int tid = threadIdx.x;
    const int j = tid & 15;
    const int s = tid >> 4;
    const int b  = blockIdx.x >> 3;
    const int jb = blockIdx.x & 7;

    const float* Gb = G  + (size_t)b * NT * NT;
    const float* Pb = P0 + (size_t)b * NT * NOBS;

#pragma unroll
    for (int it = 0; it < 4; ++it) {
        int fi = it * 256 + tid;
        int c = fi >> 6, u = (fi >> 2) & 15, v4 = fi & 3;
        ((f32x4*)gdiag)[fi] =
            *(const f32x4*)&Gb[(size_t)(c * 16 + u) * NT + c * 16 + v4 * 4];
    }
    __syncthreads();

    float pre[16];
#pragma unroll
    for (int v = 0; v < 16; ++v)
        pre[v] = Pb[(size_t)(s * 16 + v) * NOBS + jb * 16 + j];

    float* ob = out + (size_t)b * NT * NOBS + jb * 16 + j;

    for (int c = 0; c < 16; ++c) {
        if (s == c) {
            const float* gd = gdiag + c * 256;
            f32x4 r0[4], r1[4];
#pragma unroll
            for (int q = 0; q < 4; ++q) r0[q] = ((const f32x4*)gd)[q];
#pragma unroll
            for (int q = 0; q < 4; ++q) r1[q] = ((const f32x4*)(gd + 16))[q];
#pragma unroll
            for (int u = 0; u < 16; ++u) {
                const float y = 1.f / (1.f + __expf(-pre[u]));
                ylds[u * 16 + j] = y;
                ob[(size_t)(c * 16 + u) * NOBS] = y;
                const float e = ETA * y;
                const float* g = (const float*)((u & 1) ? r1 : r0);
#pragma unroll
                for (int v = 0; v < 16; ++v)
                    if (v > u) pre[v] = fmaf(e, g[v], pre[v]);
                if (u + 2 < 16) {
                    f32x4* tgt = (u & 1) ? r1 : r0;
#pragma unroll
                    for (int q = 0; q < 4; ++q)
                        tgt[q] = ((const f32x4*)(gd + (u + 2) * 16))[q];
                }
            }
        }
        __syncthreads();
        if (s > c) {
            const int col0 = s * 16;
#pragma unroll
            for (int u = 0; u < 16; ++u) {
                const float e = ETA * ylds[u * 16 + j];
                const float* grow = Gb + (size_t)(c * 16 + u) * NT + col0;
                f32x4 gv[4];
#pragma unroll
                for (int q = 0; q < 4; ++q) gv[q] = ((const f32x4*)grow)[q];
                const float* g = (const float*)gv;
#pragma unroll
                for (int v = 0; v < 16; ++v)
                    pre[v] = fmaf(e, g[v], pre[v]);
            }
        }
        __syncthreads();
    }
}

extern "C" void kernel_launch(void* const* d_in, const int* in_sizes, int n_in,
                              void* d_out, int out_size, void* d_ws, size_t ws_size,
                              hipStream_t stream)
{
    const float* X   = (const float*)d_in[0];
    const float* Wi  = (const float*)d_in[1];
    const int*   obs = (const int*)d_in[2];
    float*       out = (float*)d_out;

    unsigned short* Xb = (unsigned short*)d_ws;                          // 16 MB
    unsigned short* Wg = (unsigned short*)((char*)d_ws + (16u << 20));   //  8 MB
    float*          G  = (float*)((char*)d_ws + (24u << 20));            // 16 MB
    float*          P0 = (float*)((char*)d_ws + (40u << 20));            //  8 MB

    hipLaunchKernelGGL(k0_convert, dim3(3072), dim3(256), 0, stream,
                       X, Wi, obs, Xb, Wg);
    hipLaunchKernelGGL(k1_gemm, dim3(NB * 5), dim3(256), 0, stream,
                       Xb, Wg, G, P0);
    hipLaunchKernelGGL(k2_scan, dim3(NB * 8), dim3(256), 0, stream,
                       G, P0, out);
}